// Round 6
// baseline (1420.354 us; speedup 1.0000x reference)
//
#include <hip/hip_runtime.h>
#include <stdint.h>

#define FEAT 256
#define CODES 8192
#define NQ 16384                 // 16*32*32
#define ZQ_ELEMS (NQ * FEAT)
#define MARGIN 2e-3f             // = 2e bound on fp16 score error (R4/R5-validated)
#define NSLICE 8
#define CAP_PAIRS (1 << 17)      // 128K (expected ~18K)

typedef _Float16 f16x8 __attribute__((ext_vector_type(8)));
typedef float f32x4 __attribute__((ext_vector_type(4)));

__device__ __forceinline__ void async_lds16(void* lds, const void* g) {
  __builtin_amdgcn_global_load_lds(
      (const __attribute__((address_space(1))) void*)(uintptr_t)(g),
      (__attribute__((address_space(3))) void*)(uint32_t)(uintptr_t)(lds),
      16, 0, 0);
}

// monotone float<->uint order transform
__device__ __forceinline__ unsigned f2mono(float v) {
  unsigned u = __float_as_uint(v);
  return (u & 0x80000000u) ? ~u : (u | 0x80000000u);
}
__device__ __forceinline__ float mono2f(unsigned t) {
  unsigned u = (t & 0x80000000u) ? (t & 0x7fffffffu) : ~t;
  return __uint_as_float(u);
}

// ---------------------------------------------------------------------------
// numpy pairwise sum-of-squares replication (verified R1-R5, absmax 0).
// ---------------------------------------------------------------------------
template <int STRIDE>
__device__ __forceinline__ float pairwise256_sq(const float* __restrict__ base, int lane16) {
  const int h = lane16 >> 3, j = lane16 & 7;
  const float* p = base + (h * 128 + j) * STRIDE;
  float x = p[0];
  float r = __fmul_rn(x, x);
#pragma unroll
  for (int i = 1; i < 16; ++i) {
    float y = p[i * 8 * STRIDE];
    r = __fadd_rn(r, __fmul_rn(y, y));
  }
  r = __fadd_rn(r, __shfl_xor(r, 1, 64));
  r = __fadd_rn(r, __shfl_xor(r, 2, 64));
  r = __fadd_rn(r, __shfl_xor(r, 4, 64));
  float other = __shfl_xor(r, 8, 64);
  float lo = (h == 0) ? r : other;
  float hi = (h == 0) ? other : r;
  return __fadd_rn(lo, hi);
}

__global__ __launch_bounds__(256) void norms_kernel(const float* __restrict__ cb,
                                                    const float* __restrict__ z,
                                                    float* __restrict__ cbnorm,
                                                    float* __restrict__ znorm) {
  const int g = (blockIdx.x * 256 + threadIdx.x) >> 4;
  const int lane16 = threadIdx.x & 15;
  if (g < CODES) {
    float v = pairwise256_sq<1>(cb + g * FEAT, lane16);
    if (lane16 == 0) cbnorm[g] = v;
  } else {
    const int q = g - CODES;
    const int b = q >> 10, hw = q & 1023;
    float v = pairwise256_sq<1024>(z + b * (FEAT * 1024) + hw, lane16);
    if (lane16 == 0) znorm[q] = v;
  }
}

// ---------------------------------------------------------------------------
// convA: z fp32 -> fp16 tiles [mt][ct][r128][c32] + fp32 transpose zT[q][c]
// ---------------------------------------------------------------------------
__global__ __launch_bounds__(256) void convA(const float* __restrict__ z,
                                             char* __restrict__ At, float* __restrict__ zT) {
  __shared__ _Float16 T[128 * 40];
  __shared__ float Tf[128 * 36];
  const int t = threadIdx.x;
  const int mt = blockIdx.x >> 3, ct = blockIdx.x & 7;
  const int q0 = mt * 128, bb = q0 >> 10, hw0 = q0 & 1023;
  const int c0 = ct * 32;
#pragma unroll
  for (int it = 0; it < 16; ++it) {
    const int cc = it * 2 + (t >> 7);
    const int qi = t & 127;
    float v = z[bb * (FEAT * 1024) + (c0 + cc) * 1024 + hw0 + qi];
    T[qi * 40 + cc] = (_Float16)v;
    Tf[qi * 36 + cc] = v;
  }
  __syncthreads();
  const int r = t >> 1, h = t & 1;
  {
    float4 a = *(const float4*)&T[r * 40 + h * 16];
    float4 b = *(const float4*)&T[r * 40 + h * 16 + 8];
    char* dst = At + (size_t)(mt * 8 + ct) * 8192 + t * 32;
    *(float4*)dst = a;
    *(float4*)(dst + 16) = b;
  }
  float* zrow = zT + (size_t)(q0 + r) * FEAT + c0 + h * 16;
#pragma unroll
  for (int e = 0; e < 4; ++e)
    *(float4*)(zrow + e * 4) = *(const float4*)&Tf[r * 36 + h * 16 + e * 4];
}

// ---------------------------------------------------------------------------
// convB: cb fp32 -> fp16 tiles [nt][ct][n128][c32], scaled by 256
// ---------------------------------------------------------------------------
__global__ __launch_bounds__(256) void convB(const float* __restrict__ cb, char* __restrict__ Bt) {
  const int t = threadIdx.x;
  const int nt = blockIdx.x >> 3, ct = blockIdx.x & 7;
  const int n = t >> 1, h = t & 1;
  const float* src = cb + (size_t)(nt * 128 + n) * FEAT + ct * 32 + h * 16;
  f16x8 o0, o1;
#pragma unroll
  for (int e = 0; e < 8; ++e) o0[e] = (_Float16)(src[e] * 256.0f);
#pragma unroll
  for (int e = 0; e < 8; ++e) o1[e] = (_Float16)(src[8 + e] * 256.0f);
  char* dst = Bt + (size_t)(nt * 8 + ct) * 8192 + t * 32;
  *(f16x8*)dst = o0;
  *(f16x8*)(dst + 16) = o1;
}

// ---------------------------------------------------------------------------
// Barrier-free GEMM. A-tile (64 KB, all K) LDS-resident (staged once, one
// barrier). B loaded per-wave straight into registers from the tiled Bt
// (coalesced 1KB segments), depth-2 software prefetch, NO barriers in the
// K-loop -> loads stay in flight across MFMAs (fine-grained vmcnt).
// PASS=0: running min -> atomicMin gmin[q]. PASS=1: push (q<<13|k) for
// every score <= thr[q] = gmin[q] + MARGIN.
// ---------------------------------------------------------------------------
template <int PASS>
__device__ __forceinline__ void gemm_body(const char* __restrict__ At,
                                          const char* __restrict__ Bt,
                                          const float* __restrict__ cbnorm,
                                          unsigned* __restrict__ gmin,
                                          unsigned* __restrict__ pairs,
                                          int* __restrict__ paircount) {
  __shared__ __align__(16) char Af[65536];
  __shared__ float thrS[128];

  const int tid = threadIdx.x;
  const int slice = blockIdx.x & 7, mt = blockIdx.x >> 3;
  const int wave = tid >> 6, lane = tid & 63;
  const int wm = wave >> 1, wn = wave & 1;
  const int col = lane & 15, quad = lane >> 4;

  const int srow = wave * 32 + (lane >> 2);
  const int ss = lane & 3;
  const char* Abase = At + (size_t)(mt * 8) * 8192;

  // stage entire A tile (8 ct-chunks) into LDS, swizzled slots (R5-verified)
#pragma unroll
  for (int ct = 0; ct < 8; ++ct) {
#pragma unroll
    for (int i = 0; i < 2; ++i) {
      const int r = srow + i * 16;
      const int cs = ss ^ ((r >> 1) & 3);
      async_lds16(Af + ct * 8192 + wave * 2048 + i * 1024,
                  Abase + (size_t)ct * 8192 + r * 64 + cs * 16);
    }
  }
  if (PASS == 1 && tid < 128) thrS[tid] = mono2f(gmin[mt * 128 + tid]) + MARGIN;

  int aoff[4], bofs[4];
#pragma unroll
  for (int i = 0; i < 4; ++i) {
    const int m = wm * 64 + i * 16 + col;
    aoff[i] = m * 64 + ((quad ^ ((m >> 1) & 3)) << 4);
    const int n = wn * 64 + i * 16 + col;
    bofs[i] = n * 64 + quad * 16;  // fragment offset within an 8KB ct-chunk
  }

  int qrow[16];
#pragma unroll
  for (int row = 0; row < 16; ++row)
    qrow[row] = mt * 128 + wm * 64 + (row >> 2) * 16 + quad * 4 + (row & 3);

  __syncthreads();  // A staged (drains A-DMA), thrS ready — the ONLY barrier

  float vmin[16], thr[16];
#pragma unroll
  for (int row = 0; row < 16; ++row) {
    vmin[row] = 3.4e38f;
    thr[row] = (PASS == 1) ? thrS[qrow[row] - mt * 128] : 0.f;
  }

  // B slice base: chunk (nt,ct) at linear step = nt*8+ct
  const char* Bsl = Bt + (size_t)slice * 8 * 8 * 8192;

  f16x8 bf[2][4];
#pragma unroll
  for (int j = 0; j < 4; ++j) bf[0][j] = *(const f16x8*)(Bsl + (size_t)0 * 8192 + bofs[j]);
#pragma unroll
  for (int j = 0; j < 4; ++j) bf[1][j] = *(const f16x8*)(Bsl + (size_t)1 * 8192 + bofs[j]);

#pragma unroll
  for (int nt = 0; nt < 8; ++nt) {
    f32x4 acc[4][4];
#pragma unroll
    for (int i = 0; i < 4; ++i)
#pragma unroll
      for (int j = 0; j < 4; ++j) acc[i][j] = (f32x4){0.f, 0.f, 0.f, 0.f};

#pragma unroll
    for (int ct = 0; ct < 8; ++ct) {
      const int step = nt * 8 + ct;
      f16x8 af[4];
#pragma unroll
      for (int i = 0; i < 4; ++i)
        af[i] = *(const f16x8*)(Af + ct * 8192 + aoff[i]);
      // consume current buffer
#pragma unroll
      for (int i = 0; i < 4; ++i)
#pragma unroll
        for (int j = 0; j < 4; ++j)
          acc[i][j] = __builtin_amdgcn_mfma_f32_16x16x32_f16(af[i], bf[ct & 1][j], acc[i][j], 0, 0, 0);
      // refill same buffer with step+2 (depth-2 prefetch, period 2)
      if (step + 2 < 64) {
#pragma unroll
        for (int j = 0; j < 4; ++j)
          bf[ct & 1][j] = *(const f16x8*)(Bsl + (size_t)(step + 2) * 8192 + bofs[j]);
      }
    }
    // scoring
    const int k0 = (slice * 8 + nt) * 128;
#pragma unroll
    for (int j = 0; j < 4; ++j) {
      const int k = k0 + wn * 64 + j * 16 + col;
      const float cn = cbnorm[k];
#pragma unroll
      for (int i = 0; i < 4; ++i)
#pragma unroll
        for (int r = 0; r < 4; ++r) {
          const int row = i * 4 + r;
          const float s = __builtin_fmaf(acc[i][j][r], -0.0078125f, cn);
          if (PASS == 0) {
            vmin[row] = fminf(vmin[row], s);
          } else {
            if (s <= thr[row]) {
              const int slot = atomicAdd(paircount, 1);
              if (slot < CAP_PAIRS) pairs[slot] = ((unsigned)qrow[row] << 13) | (unsigned)k;
            }
          }
        }
    }
  }

  if (PASS == 0) {
#pragma unroll
    for (int row = 0; row < 16; ++row) {
      float v = vmin[row];
      v = fminf(v, __shfl_xor(v, 1, 64));
      v = fminf(v, __shfl_xor(v, 2, 64));
      v = fminf(v, __shfl_xor(v, 4, 64));
      v = fminf(v, __shfl_xor(v, 8, 64));
      if (col == 0) atomicMin(&gmin[qrow[row]], f2mono(v));
    }
  }
}

__global__ __launch_bounds__(256, 2) void gemm_pass1(const char* __restrict__ At,
                                                     const char* __restrict__ Bt,
                                                     const float* __restrict__ cbnorm,
                                                     unsigned* __restrict__ gmin) {
  gemm_body<0>(At, Bt, cbnorm, gmin, nullptr, nullptr);
}

__global__ __launch_bounds__(256, 2) void gemm_pass2(const char* __restrict__ At,
                                                     const char* __restrict__ Bt,
                                                     const float* __restrict__ cbnorm,
                                                     unsigned* __restrict__ gmin,
                                                     unsigned* __restrict__ pairs,
                                                     int* __restrict__ paircount) {
  gemm_body<1>(At, Bt, cbnorm, gmin, pairs, paircount);
}

// ---------------------------------------------------------------------------
// Exact fp32 rescore of all pushed pairs (np chain, R4/R5-verified).
// One wave per pair; winner per q via packed atomicMin (ties -> min k).
// ---------------------------------------------------------------------------
__global__ __launch_bounds__(256) void exact_cand(const float* __restrict__ zT,
                                                  const float* __restrict__ cb,
                                                  const float* __restrict__ cbnorm,
                                                  const float* __restrict__ znorm,
                                                  const unsigned* __restrict__ pairs,
                                                  const int* __restrict__ paircount,
                                                  unsigned long long* __restrict__ packed) {
  const int cnt = min(*paircount, CAP_PAIRS);
  const int gw = (blockIdx.x * 256 + threadIdx.x) >> 6;
  const int nw = (gridDim.x * 256) >> 6;
  const int lane = threadIdx.x & 63;
  for (int p = gw; p < cnt; p += nw) {
    const unsigned qk = pairs[p];
    const int q = qk >> 13, k = qk & 8191;
    const float4 cv = ((const float4*)(cb + (size_t)k * FEAT))[lane];
    const float4 zv = ((const float4*)(zT + (size_t)q * FEAT))[lane];
    float d = __builtin_fmaf(zv.w, cv.w,
              __builtin_fmaf(zv.z, cv.z,
              __builtin_fmaf(zv.y, cv.y, __fmul_rn(zv.x, cv.x))));
#pragma unroll
    for (int dd = 1; dd < 64; dd <<= 1) d = __fadd_rn(d, __shfl_xor(d, dd, 64));
    const float s = __fadd_rn(__fadd_rn(__fmul_rn(-2.0f, d), znorm[q]), cbnorm[k]);
    if (lane == 0) {
      const unsigned long long key = ((unsigned long long)f2mono(s) << 32) | (unsigned)k;
      atomicMin(&packed[q], key);
    }
  }
}

// ---------------------------------------------------------------------------
// Gather: zq[b][c][hw] = cb[idx]; idx as float appended after zq.
// ---------------------------------------------------------------------------
__global__ __launch_bounds__(256) void vq_gather(const float* __restrict__ cb,
                                                 const unsigned long long* __restrict__ packed,
                                                 float* __restrict__ out) {
  const int q0 = blockIdx.x * 64;
  const int nl = threadIdx.x & 63;
  const int cg = threadIdx.x >> 6;
  const int q = q0 + nl;
  const int kq = (int)((unsigned)packed[q] & 8191u);
  const int b = q >> 10, hw = q & 1023;
  const float4* cb4 = (const float4*)cb;
#pragma unroll
  for (int t = 0; t < 16; ++t) {
    const int cc = cg + t * 4;
    const float4 v = cb4[kq * 64 + cc];
    const int base = b * (FEAT * 1024) + (cc * 4) * 1024 + hw;
    out[base] = v.x;
    out[base + 1024] = v.y;
    out[base + 2048] = v.z;
    out[base + 3072] = v.w;
  }
  if (threadIdx.x < 64) {
    const int qq = q0 + threadIdx.x;
    out[ZQ_ELEMS + qq] = (float)(int)((unsigned)packed[qq] & 8191u);
  }
}

extern "C" void kernel_launch(void* const* d_in, const int* in_sizes, int n_in,
                              void* d_out, int out_size, void* d_ws, size_t ws_size,
                              hipStream_t stream) {
  const float* z = (const float*)d_in[0];
  const float* cb = (const float*)d_in[1];
  char* w = (char*)d_ws;
  // ws layout (~30.2 MB)
  char* At = w;                                            // 8 MB
  char* Bt = w + 8388608;                                  // 4 MB
  float* zT = (float*)(w + 12582912);                      // 16 MB
  float* cbnorm = (float*)(w + 29360128);                  // 32 KB
  float* znorm = (float*)(w + 29392896);                   // 64 KB
  unsigned* gmin = (unsigned*)(w + 29458432);              // 64 KB
  int* paircount = (int*)(w + 29523968);                   // 256 B
  unsigned* pairs = (unsigned*)(w + 29524224);             // 512 KB
  unsigned long long* packed = (unsigned long long*)(w + 30048512);  // 128 KB

  hipMemsetAsync(paircount, 0, 256, stream);
  hipMemsetAsync(gmin, 0xFF, NQ * sizeof(unsigned), stream);
  hipMemsetAsync(packed, 0xFF, NQ * sizeof(unsigned long long), stream);
  norms_kernel<<<(CODES + NQ) / 16, 256, 0, stream>>>(cb, z, cbnorm, znorm);
  convA<<<1024, 256, 0, stream>>>(z, At, zT);
  convB<<<512, 256, 0, stream>>>(cb, Bt);
  gemm_pass1<<<(NQ / 128) * NSLICE, 256, 0, stream>>>(At, Bt, cbnorm, gmin);
  gemm_pass2<<<(NQ / 128) * NSLICE, 256, 0, stream>>>(At, Bt, cbnorm, gmin, pairs, paircount);
  exact_cand<<<512, 256, 0, stream>>>(zT, cb, cbnorm, znorm, pairs, paircount, packed);
  vq_gather<<<NQ / 64, 256, 0, stream>>>(cb, packed, (float*)d_out);
}

// Round 7
// 573.517 us; speedup vs baseline: 2.4766x; 2.4766x over previous
//
#include <hip/hip_runtime.h>
#include <stdint.h>

#define FEAT 256
#define CODES 8192
#define NQ 16384                 // 16*32*32
#define ZQ_ELEMS (NQ * FEAT)
#define MARGIN 2e-3f             // = 2e bound on fp16 score error (R4/R5-validated)
#define NSLICE 8
#define CAP_PAIRS (1 << 17)      // 128K (expected ~18K)

typedef _Float16 f16x8 __attribute__((ext_vector_type(8)));
typedef float f32x4 __attribute__((ext_vector_type(4)));

__device__ __forceinline__ void async_lds16(void* lds, const void* g) {
  __builtin_amdgcn_global_load_lds(
      (const __attribute__((address_space(1))) void*)(uintptr_t)(g),
      (__attribute__((address_space(3))) void*)(uint32_t)(uintptr_t)(lds),
      16, 0, 0);
}

// monotone float<->uint order transform
__device__ __forceinline__ unsigned f2mono(float v) {
  unsigned u = __float_as_uint(v);
  return (u & 0x80000000u) ? ~u : (u | 0x80000000u);
}
__device__ __forceinline__ float mono2f(unsigned t) {
  unsigned u = (t & 0x80000000u) ? (t & 0x7fffffffu) : ~t;
  return __uint_as_float(u);
}

// ---------------------------------------------------------------------------
// numpy pairwise sum-of-squares replication (verified R1-R6, absmax 0).
// ---------------------------------------------------------------------------
template <int STRIDE>
__device__ __forceinline__ float pairwise256_sq(const float* __restrict__ base, int lane16) {
  const int h = lane16 >> 3, j = lane16 & 7;
  const float* p = base + (h * 128 + j) * STRIDE;
  float x = p[0];
  float r = __fmul_rn(x, x);
#pragma unroll
  for (int i = 1; i < 16; ++i) {
    float y = p[i * 8 * STRIDE];
    r = __fadd_rn(r, __fmul_rn(y, y));
  }
  r = __fadd_rn(r, __shfl_xor(r, 1, 64));
  r = __fadd_rn(r, __shfl_xor(r, 2, 64));
  r = __fadd_rn(r, __shfl_xor(r, 4, 64));
  float other = __shfl_xor(r, 8, 64);
  float lo = (h == 0) ? r : other;
  float hi = (h == 0) ? other : r;
  return __fadd_rn(lo, hi);
}

__global__ __launch_bounds__(256) void norms_kernel(const float* __restrict__ cb,
                                                    const float* __restrict__ z,
                                                    float* __restrict__ cbnorm,
                                                    float* __restrict__ znorm) {
  const int g = (blockIdx.x * 256 + threadIdx.x) >> 4;
  const int lane16 = threadIdx.x & 15;
  if (g < CODES) {
    float v = pairwise256_sq<1>(cb + g * FEAT, lane16);
    if (lane16 == 0) cbnorm[g] = v;
  } else {
    const int q = g - CODES;
    const int b = q >> 10, hw = q & 1023;
    float v = pairwise256_sq<1024>(z + b * (FEAT * 1024) + hw, lane16);
    if (lane16 == 0) znorm[q] = v;
  }
}

// ---------------------------------------------------------------------------
// convA: z fp32 -> fp16 tiles [mt64][ct][r64][c32] (4 KB chunks) + fp32 zT
// ---------------------------------------------------------------------------
__global__ __launch_bounds__(256) void convA(const float* __restrict__ z,
                                             char* __restrict__ At, float* __restrict__ zT) {
  __shared__ _Float16 T[128 * 40];
  __shared__ float Tf[128 * 36];
  const int t = threadIdx.x;
  const int mt = blockIdx.x >> 3, ct = blockIdx.x & 7;
  const int q0 = mt * 128, bb = q0 >> 10, hw0 = q0 & 1023;
  const int c0 = ct * 32;
#pragma unroll
  for (int it = 0; it < 16; ++it) {
    const int cc = it * 2 + (t >> 7);
    const int qi = t & 127;
    float v = z[bb * (FEAT * 1024) + (c0 + cc) * 1024 + hw0 + qi];
    T[qi * 40 + cc] = (_Float16)v;
    Tf[qi * 36 + cc] = v;
  }
  __syncthreads();
  const int r = t >> 1, h = t & 1;
  {
    float4 a = *(const float4*)&T[r * 40 + h * 16];
    float4 b = *(const float4*)&T[r * 40 + h * 16 + 8];
    const int tile64 = mt * 2 + (r >> 6);
    char* dst = At + (size_t)(tile64 * 8 + ct) * 4096 + (r & 63) * 64 + h * 32;
    *(float4*)dst = a;
    *(float4*)(dst + 16) = b;
  }
  float* zrow = zT + (size_t)(q0 + r) * FEAT + c0 + h * 16;
#pragma unroll
  for (int e = 0; e < 4; ++e)
    *(float4*)(zrow + e * 4) = *(const float4*)&Tf[r * 36 + h * 16 + e * 4];
}

// ---------------------------------------------------------------------------
// convB: cb fp32 -> fp16 tiles [nt128][ct][n128][c32] (8 KB chunks), x256
// ---------------------------------------------------------------------------
__global__ __launch_bounds__(256) void convB(const float* __restrict__ cb, char* __restrict__ Bt) {
  const int t = threadIdx.x;
  const int nt = blockIdx.x >> 3, ct = blockIdx.x & 7;
  const int n = t >> 1, h = t & 1;
  const float* src = cb + (size_t)(nt * 128 + n) * FEAT + ct * 32 + h * 16;
  f16x8 o0, o1;
#pragma unroll
  for (int e = 0; e < 8; ++e) o0[e] = (_Float16)(src[e] * 256.0f);
#pragma unroll
  for (int e = 0; e < 8; ++e) o1[e] = (_Float16)(src[8 + e] * 256.0f);
  char* dst = Bt + (size_t)(nt * 8 + ct) * 8192 + t * 32;
  *(f16x8*)dst = o0;
  *(f16x8*)(dst + 16) = o1;
}

// ---------------------------------------------------------------------------
// Barrier-free GEMM, 64q x 1024k per block (2048 blocks, slice = blk&7 pins
// each XCD to one 512 KB L2-resident B slice). A (32 KB, all K) LDS-resident,
// staged once. B per-wave register loads, depth-4 prefetch (bf[ct&3] static
// rotation), NO barriers in K-loop. nt-loop NOT unrolled (R6 spill fix).
// PASS=0: running min -> LDS reduce -> atomicMin gmin[q].
// PASS=1: push (q<<13|k) for every score <= thr[q] = gmin[q] + MARGIN.
// ---------------------------------------------------------------------------
template <int PASS>
__device__ __forceinline__ void gemm_body(const char* __restrict__ At,
                                          const char* __restrict__ Bt,
                                          const float* __restrict__ cbnorm,
                                          unsigned* __restrict__ gmin,
                                          unsigned* __restrict__ pairs,
                                          int* __restrict__ paircount) {
  __shared__ __align__(16) char Af[32768];
  __shared__ float cbn[1024];
  __shared__ float thrS[64];
  __shared__ float mvS[64 * 4];

  const int tid = threadIdx.x;
  const int slice = blockIdx.x & 7, mt = blockIdx.x >> 3;
  const int wave = tid >> 6, lane = tid & 63;
  const int col = lane & 15, quad = lane >> 4;
  const int srow16 = lane >> 2;   // 0..15
  const int ss = lane & 3;

  // stage A tile: wave w stages rows w*16..w*16+15 for each ct chunk
  const char* Abase = At + (size_t)(mt * 8) * 4096;
#pragma unroll
  for (int ct = 0; ct < 8; ++ct) {
    const int r = wave * 16 + srow16;
    const int cs = ss ^ ((r >> 1) & 3);
    async_lds16(Af + ct * 4096 + wave * 1024, Abase + (size_t)ct * 4096 + r * 64 + cs * 16);
  }
  // cbnorm slice -> LDS (4 KB)
  ((float4*)cbn)[tid] = ((const float4*)(cbnorm + slice * 1024))[tid];
  if (PASS == 1 && tid < 64) thrS[tid] = mono2f(gmin[mt * 64 + tid]) + MARGIN;

  int aoff[4];
#pragma unroll
  for (int i = 0; i < 4; ++i) {
    const int m = i * 16 + col;
    aoff[i] = m * 64 + ((quad ^ ((m >> 1) & 3)) << 4);
  }
  int bofs[2];
#pragma unroll
  for (int j = 0; j < 2; ++j) {
    const int n = wave * 32 + j * 16 + col;
    bofs[j] = n * 64 + quad * 16;
  }

  __syncthreads();  // A DMA drained, cbn/thrS visible — the ONLY K-barrier

  float vmin[16], thr[16];
#pragma unroll
  for (int e = 0; e < 16; ++e) {
    vmin[e] = 3.4e38f;
    thr[e] = (PASS == 1) ? thrS[(e >> 2) * 16 + quad * 4 + (e & 3)] : 0.f;
  }

  const char* Bsl = Bt + (size_t)slice * 64 * 8192;  // contiguous 512 KB slice

  // prologue: fill 4 prefetch buffers (steps 0..3)
  f16x8 bf[4][2];
#pragma unroll
  for (int s = 0; s < 4; ++s)
#pragma unroll
    for (int j = 0; j < 2; ++j)
      bf[s][j] = *(const f16x8*)(Bsl + (size_t)s * 8192 + bofs[j]);

#pragma unroll 1
  for (int nt = 0; nt < 8; ++nt) {
    f32x4 acc[4][2];
#pragma unroll
    for (int i = 0; i < 4; ++i)
#pragma unroll
      for (int j = 0; j < 2; ++j) acc[i][j] = (f32x4){0.f, 0.f, 0.f, 0.f};

#pragma unroll
    for (int ct = 0; ct < 8; ++ct) {
      const int step = nt * 8 + ct;       // (step & 3) == (ct & 3): static idx
      f16x8 af[4];
#pragma unroll
      for (int i = 0; i < 4; ++i) af[i] = *(const f16x8*)(Af + ct * 4096 + aoff[i]);
#pragma unroll
      for (int i = 0; i < 4; ++i)
#pragma unroll
        for (int j = 0; j < 2; ++j)
          acc[i][j] = __builtin_amdgcn_mfma_f32_16x16x32_f16(af[i], bf[ct & 3][j], acc[i][j], 0, 0, 0);
      const int pf = (step + 4) & 63;     // wrap at tail: harmless dead loads
#pragma unroll
      for (int j = 0; j < 2; ++j)
        bf[ct & 3][j] = *(const f16x8*)(Bsl + (size_t)pf * 8192 + bofs[j]);
    }
    // scoring for this 128-code tile
#pragma unroll
    for (int j = 0; j < 2; ++j) {
      const int kl = nt * 128 + wave * 32 + j * 16 + col;
      const float cn = cbn[kl];
      const int k = slice * 1024 + kl;
#pragma unroll
      for (int i = 0; i < 4; ++i)
#pragma unroll
        for (int r = 0; r < 4; ++r) {
          const float s = __builtin_fmaf(acc[i][j][r], -0.0078125f, cn);
          if (PASS == 0) {
            vmin[i * 4 + r] = fminf(vmin[i * 4 + r], s);
          } else {
            if (s <= thr[i * 4 + r]) {
              const unsigned q = (unsigned)(mt * 64 + i * 16 + quad * 4 + r);
              const int slot = atomicAdd(paircount, 1);
              if (slot < CAP_PAIRS) pairs[slot] = (q << 13) | (unsigned)k;
            }
          }
        }
    }
  }

  if (PASS == 0) {
#pragma unroll
    for (int e = 0; e < 16; ++e) {
      float v = vmin[e];
      v = fminf(v, __shfl_xor(v, 1, 64));
      v = fminf(v, __shfl_xor(v, 2, 64));
      v = fminf(v, __shfl_xor(v, 4, 64));
      v = fminf(v, __shfl_xor(v, 8, 64));
      if (col == 0) mvS[((e >> 2) * 16 + quad * 4 + (e & 3)) * 4 + wave] = v;
    }
    __syncthreads();
    if (tid < 64) {
      const float m = fminf(fminf(mvS[tid * 4], mvS[tid * 4 + 1]),
                            fminf(mvS[tid * 4 + 2], mvS[tid * 4 + 3]));
      atomicMin(&gmin[mt * 64 + tid], f2mono(m));
    }
  }
}

__global__ __launch_bounds__(256, 3) void gemm_pass1(const char* __restrict__ At,
                                                     const char* __restrict__ Bt,
                                                     const float* __restrict__ cbnorm,
                                                     unsigned* __restrict__ gmin) {
  gemm_body<0>(At, Bt, cbnorm, gmin, nullptr, nullptr);
}

__global__ __launch_bounds__(256, 3) void gemm_pass2(const char* __restrict__ At,
                                                     const char* __restrict__ Bt,
                                                     const float* __restrict__ cbnorm,
                                                     unsigned* __restrict__ gmin,
                                                     unsigned* __restrict__ pairs,
                                                     int* __restrict__ paircount) {
  gemm_body<1>(At, Bt, cbnorm, gmin, pairs, paircount);
}

// ---------------------------------------------------------------------------
// Exact fp32 rescore of all pushed pairs (np chain, R4-R6 verified).
// One wave per pair; winner per q via packed atomicMin (ties -> min k).
// ---------------------------------------------------------------------------
__global__ __launch_bounds__(256) void exact_cand(const float* __restrict__ zT,
                                                  const float* __restrict__ cb,
                                                  const float* __restrict__ cbnorm,
                                                  const float* __restrict__ znorm,
                                                  const unsigned* __restrict__ pairs,
                                                  const int* __restrict__ paircount,
                                                  unsigned long long* __restrict__ packed) {
  const int cnt = min(*paircount, CAP_PAIRS);
  const int gw = (blockIdx.x * 256 + threadIdx.x) >> 6;
  const int nw = (gridDim.x * 256) >> 6;
  const int lane = threadIdx.x & 63;
  for (int p = gw; p < cnt; p += nw) {
    const unsigned qk = pairs[p];
    const int q = qk >> 13, k = qk & 8191;
    const float4 cv = ((const float4*)(cb + (size_t)k * FEAT))[lane];
    const float4 zv = ((const float4*)(zT + (size_t)q * FEAT))[lane];
    float d = __builtin_fmaf(zv.w, cv.w,
              __builtin_fmaf(zv.z, cv.z,
              __builtin_fmaf(zv.y, cv.y, __fmul_rn(zv.x, cv.x))));
#pragma unroll
    for (int dd = 1; dd < 64; dd <<= 1) d = __fadd_rn(d, __shfl_xor(d, dd, 64));
    const float s = __fadd_rn(__fadd_rn(__fmul_rn(-2.0f, d), znorm[q]), cbnorm[k]);
    if (lane == 0) {
      const unsigned long long key = ((unsigned long long)f2mono(s) << 32) | (unsigned)k;
      atomicMin(&packed[q], key);
    }
  }
}

// ---------------------------------------------------------------------------
// Gather: zq[b][c][hw] = cb[idx]; idx as float appended after zq.
// ---------------------------------------------------------------------------
__global__ __launch_bounds__(256) void vq_gather(const float* __restrict__ cb,
                                                 const unsigned long long* __restrict__ packed,
                                                 float* __restrict__ out) {
  const int q0 = blockIdx.x * 64;
  const int nl = threadIdx.x & 63;
  const int cg = threadIdx.x >> 6;
  const int q = q0 + nl;
  const int kq = (int)((unsigned)packed[q] & 8191u);
  const int b = q >> 10, hw = q & 1023;
  const float4* cb4 = (const float4*)cb;
#pragma unroll
  for (int t = 0; t < 16; ++t) {
    const int cc = cg + t * 4;
    const float4 v = cb4[kq * 64 + cc];
    const int base = b * (FEAT * 1024) + (cc * 4) * 1024 + hw;
    out[base] = v.x;
    out[base + 1024] = v.y;
    out[base + 2048] = v.z;
    out[base + 3072] = v.w;
  }
  if (threadIdx.x < 64) {
    const int qq = q0 + threadIdx.x;
    out[ZQ_ELEMS + qq] = (float)(int)((unsigned)packed[qq] & 8191u);
  }
}

extern "C" void kernel_launch(void* const* d_in, const int* in_sizes, int n_in,
                              void* d_out, int out_size, void* d_ws, size_t ws_size,
                              hipStream_t stream) {
  const float* z = (const float*)d_in[0];
  const float* cb = (const float*)d_in[1];
  char* w = (char*)d_ws;
  // ws layout (~30.2 MB)
  char* At = w;                                            // 8 MB
  char* Bt = w + 8388608;                                  // 4 MB
  float* zT = (float*)(w + 12582912);                      // 16 MB
  float* cbnorm = (float*)(w + 29360128);                  // 32 KB
  float* znorm = (float*)(w + 29392896);                   // 64 KB
  unsigned* gmin = (unsigned*)(w + 29458432);              // 64 KB
  int* paircount = (int*)(w + 29523968);                   // 256 B
  unsigned* pairs = (unsigned*)(w + 29524224);             // 512 KB
  unsigned long long* packed = (unsigned long long*)(w + 30048512);  // 128 KB

  hipMemsetAsync(paircount, 0, 256, stream);
  hipMemsetAsync(gmin, 0xFF, NQ * sizeof(unsigned), stream);
  hipMemsetAsync(packed, 0xFF, NQ * sizeof(unsigned long long), stream);
  norms_kernel<<<(CODES + NQ) / 16, 256, 0, stream>>>(cb, z, cbnorm, znorm);
  convA<<<1024, 256, 0, stream>>>(z, At, zT);
  convB<<<512, 256, 0, stream>>>(cb, Bt);
  gemm_pass1<<<(NQ / 64) * NSLICE, 256, 0, stream>>>(At, Bt, cbnorm, gmin);
  gemm_pass2<<<(NQ / 64) * NSLICE, 256, 0, stream>>>(At, Bt, cbnorm, gmin, pairs, paircount);
  exact_cand<<<512, 256, 0, stream>>>(zT, cb, cbnorm, znorm, pairs, paircount, packed);
  vq_gather<<<NQ / 64, 256, 0, stream>>>(cb, packed, (float*)d_out);
}